// Round 1
// 364.895 us; speedup vs baseline: 1.1854x; 1.1854x over previous
//
#include <hip/hip_runtime.h>

#define N_NODES 100000
#define N_EDGES 3200000
#define D 128

#define K1C    391        // coarse buckets: bucket = dst >> 8 (256 nodes each)
#define CHUNK  6144       // edges per partition block
#define NCHUNK 521        // ceil(N_EDGES / CHUNK)

// ---------------------------------------------------------------------------
// Workspace layout (bytes). Total ~77.3 MB; ws >= 78,000,512 proven round 2.
// ---------------------------------------------------------------------------
static const size_t OFF_SB    = 0;           // S bf16 packed: N*64 uints = 25.6 MB
static const size_t OFF_REC   = 25600000;    // E int2 (coarse-partitioned)
static const size_t OFF_SORT2 = 51200000;    // E int2 (fine-sorted)
static const size_t OFF_OFFS  = 76800000;    // N ints
static const size_t OFF_GHIST = 77200000;
static const size_t OFF_BOFFS = 77204096;
static const size_t OFF_GCUR  = 77208192;

typedef __attribute__((ext_vector_type(8))) short bf16x8;
typedef __attribute__((ext_vector_type(4))) float f32x4;

__device__ __forceinline__ unsigned short f2bf(float f) {
    unsigned u = __float_as_uint(f);
    return (unsigned short)((u + 0x7FFFu + ((u >> 16) & 1u)) >> 16);   // RNE
}

// ---------------------------------------------------------------------------
// S = X @ W via MFMA — verified in round 5 (absmax matched VALU-bf16 path).
// ---------------------------------------------------------------------------
__global__ __launch_bounds__(256) void gemm_mfma(const float* __restrict__ X,
                                                 const float* __restrict__ W,
                                                 unsigned* __restrict__ Sb) {
    __shared__ __align__(16) union {
        unsigned short wfrag[8][4][64][8];  // [ct][kt][lane][j] = 32 KB
        unsigned       stage[4][32][68];    // [wave][row][dword] = 34 KB
    } u;

    const int t    = threadIdx.x;
    const int lane = t & 63;
    const int wave = t >> 6;
    const int quad = lane >> 4;
    const int li   = lane & 15;
    const int rowBase = blockIdx.x * 128;

    // stage W[k][n] fp32 -> pre-packed bf16 B-fragments
    for (int i = t; i < D * D; i += 256) {
        int k = i >> 7, n = i & 127;
        u.wfrag[n >> 4][k >> 5][((k >> 3) & 3) * 16 + (n & 15)][k & 7] = f2bf(W[i]);
    }
    __syncthreads();

    f32x4 acc[2][8];
#pragma unroll
    for (int rt = 0; rt < 2; ++rt)
#pragma unroll
        for (int ct = 0; ct < 8; ++ct)
            acc[rt][ct] = (f32x4){0.f, 0.f, 0.f, 0.f};

#pragma unroll
    for (int kt = 0; kt < 4; ++kt) {
        bf16x8 a[2];
#pragma unroll
        for (int rt = 0; rt < 2; ++rt) {
            int row = rowBase + wave * 32 + rt * 16 + li;
            if (row >= N_NODES) row = N_NODES - 1;           // clamp; store masked
            const float* xp = X + (size_t)row * D + kt * 32 + quad * 8;
            float4 f0 = ((const float4*)xp)[0];
            float4 f1 = ((const float4*)xp)[1];
            bf16x8 av;
            av[0] = (short)f2bf(f0.x); av[1] = (short)f2bf(f0.y);
            av[2] = (short)f2bf(f0.z); av[3] = (short)f2bf(f0.w);
            av[4] = (short)f2bf(f1.x); av[5] = (short)f2bf(f1.y);
            av[6] = (short)f2bf(f1.z); av[7] = (short)f2bf(f1.w);
            a[rt] = av;
        }
#pragma unroll
        for (int ct = 0; ct < 8; ++ct) {
            bf16x8 b = *(const bf16x8*)&u.wfrag[ct][kt][lane][0];
            acc[0][ct] = __builtin_amdgcn_mfma_f32_16x16x32_bf16(a[0], b, acc[0][ct], 0, 0, 0);
            acc[1][ct] = __builtin_amdgcn_mfma_f32_16x16x32_bf16(a[1], b, acc[1][ct], 0, 0, 0);
        }
    }
    __syncthreads();

    unsigned short* sw = (unsigned short*)&u.stage[wave][0][0];  // 32 x 136 bf16
#pragma unroll
    for (int rt = 0; rt < 2; ++rt)
#pragma unroll
        for (int r = 0; r < 4; ++r) {
            int lrow = rt * 16 + quad * 4 + r;
#pragma unroll
            for (int ct = 0; ct < 8; ++ct)
                sw[lrow * 136 + ct * 16 + li] = f2bf(acc[rt][ct][r]);
        }
    for (int lrow = 0; lrow < 32; ++lrow) {
        int node = rowBase + wave * 32 + lrow;
        if (node < N_NODES)
            Sb[(size_t)node * 64 + lane] = ((unsigned*)sw)[lrow * 68 + lane];
    }
}

// ---------------------------------------------------------------------------
// Coarse histogram over K1C buckets (bucket = dst >> 8)
// ---------------------------------------------------------------------------
__global__ __launch_bounds__(256) void hist_coarse(const int* __restrict__ edst,
                                                   int* __restrict__ ghist) {
    __shared__ int h[K1C];
    for (int i = threadIdx.x; i < K1C; i += 256) h[i] = 0;
    __syncthreads();
    for (int e = blockIdx.x * 256 + threadIdx.x; e < N_EDGES; e += gridDim.x * 256)
        atomicAdd(&h[edst[e] >> 8], 1);
    __syncthreads();
    for (int i = threadIdx.x; i < K1C; i += 256)
        if (h[i]) atomicAdd(&ghist[i], h[i]);
}

__global__ __launch_bounds__(256) void scan_coarse(const int* __restrict__ ghist,
                                                   int* __restrict__ boffs,
                                                   int* __restrict__ gcursor) {
    __shared__ int sc[256];
    const int t = threadIdx.x;
    int v[2]; int s = 0;
#pragma unroll
    for (int j = 0; j < 2; ++j) {
        int idx = t * 2 + j;
        v[j] = (idx < K1C) ? ghist[idx] : 0;
        s += v[j];
    }
    sc[t] = s;
    __syncthreads();
    for (int off = 1; off < 256; off <<= 1) {
        int u = (t >= off) ? sc[t - off] : 0;
        __syncthreads();
        sc[t] += u;
        __syncthreads();
    }
    int run = (t == 0) ? 0 : sc[t - 1];
#pragma unroll
    for (int j = 0; j < 2; ++j) {
        int idx = t * 2 + j;
        if (idx < K1C) { boffs[idx] = run; gcursor[idx] = run; }
        run += v[j];
    }
    if (t == 255) boffs[K1C] = run;
}

// ---------------------------------------------------------------------------
// LDS-staged coarse partition, two-pass-per-block (hist then re-read+scatter).
// CHUNK=6144 / 512 threads: ~15.7 records per (block,bucket) => ~126 B write
// fragments (vs 21 B before) and 7.7x fewer global cursor atomics.
// rec.x = src | (dst&255)<<17 ; rec.y = val bits.
// ---------------------------------------------------------------------------
__global__ __launch_bounds__(512) void partition_edges(
        const int* __restrict__ esrc,
        const int* __restrict__ edst,
        const float* __restrict__ eval,
        int* __restrict__ gcursor,
        int2* __restrict__ rec_out) {
    __shared__ int  hist[K1C];
    __shared__ int  lofs[K1C];
    __shared__ int  gbase[K1C];
    __shared__ int  cur[K1C];
    __shared__ int  sc[512];
    __shared__ int2 staged[CHUNK];
    __shared__ unsigned short bkt[CHUNK];

    const int t   = threadIdx.x;
    const int e0  = blockIdx.x * CHUNK;
    const int cnt = min(CHUNK, N_EDGES - e0);

    for (int i = t; i < K1C; i += 512) hist[i] = 0;
    __syncthreads();

    // pass 1: block-local histogram (edst read is coalesced; re-read below is L2-hot)
    for (int i = t; i < cnt; i += 512)
        atomicAdd(&hist[edst[e0 + i] >> 8], 1);
    __syncthreads();

    // block scan: one bucket per thread (K1C=391 <= 512)
    int hv = (t < K1C) ? hist[t] : 0;
    sc[t] = hv;
    __syncthreads();
    for (int off = 1; off < 512; off <<= 1) {
        int u = (t >= off) ? sc[t - off] : 0;
        __syncthreads();
        sc[t] += u;
        __syncthreads();
    }
    if (t < K1C) {
        int excl = sc[t] - hv;
        lofs[t]  = excl;
        cur[t]   = excl;
        gbase[t] = hv ? atomicAdd(&gcursor[t], hv) : 0;
    }
    __syncthreads();

    // pass 2: re-read edges, scatter into LDS staging (bucket-sorted)
    for (int i = t; i < cnt; i += 512) {
        int e = e0 + i;
        int d = edst[e];
        int b = d >> 8;
        int pos = atomicAdd(&cur[b], 1);
        staged[pos] = make_int2(esrc[e] | ((d & 255) << 17), __float_as_int(eval[e]));
        bkt[pos] = (unsigned short)b;
    }
    __syncthreads();

    // writeout: contiguous per-bucket runs (~126 B each)
    for (int i = t; i < cnt; i += 512) {
        int bb = bkt[i];
        rec_out[gbase[bb] + (i - lofs[bb])] = staged[i];
    }
}

// ---------------------------------------------------------------------------
// Fine sort within each 256-node coarse bucket. Scatter window ~65 KB ->
// L2-resident. Emits per-node segment offsets. One node per thread.
// ---------------------------------------------------------------------------
__global__ __launch_bounds__(256) void fine_sort(
        const int2* __restrict__ rec,
        const int* __restrict__ boffs,
        int* __restrict__ offs,
        int2* __restrict__ sorted2) {
    __shared__ int h[256];
    __shared__ int cur[256];
    __shared__ int sc[256];

    const int c   = blockIdx.x;
    const int t   = threadIdx.x;
    const int beg = boffs[c];
    const int end = boffs[c + 1];

    h[t] = 0;
    __syncthreads();

    for (int i = beg + t; i < end; i += 256)
        atomicAdd(&h[(rec[i].x >> 17) & 255], 1);
    __syncthreads();

    sc[t] = h[t];
    __syncthreads();
    for (int off = 1; off < 256; off <<= 1) {
        int u = (t >= off) ? sc[t - off] : 0;
        __syncthreads();
        sc[t] += u;
        __syncthreads();
    }
    {
        int excl = sc[t] - h[t];
        int node = c * 256 + t;
        if (node < N_NODES) offs[node] = beg + excl;
        cur[t] = beg + excl;
    }
    __syncthreads();

    for (int i = beg + t; i < end; i += 256) {
        int2 q = rec[i];
        int dl = (q.x >> 17) & 255;
        int p = atomicAdd(&cur[dl], 1);
        sorted2[p] = make_int2(q.x & 0x1FFFF, q.y);
    }
}

// ---------------------------------------------------------------------------
// Wave-per-node segmented reduce, half-wave record pairing:
// lanes 0-31 gather record 2j, lanes 32-63 gather record 2j+1 (uint2 =
// 8 B/lane = feats 4hl..4hl+3). 4 pairs unrolled -> 4 outstanding 512 B
// gathers/wave. Halves combined via shfl(lane^32); lanes 0-31 store float4.
// Tail records are zero-padded (val=0) so no masking needed in the loop.
// ---------------------------------------------------------------------------
__global__ __launch_bounds__(256) void reduce_segments(
        const unsigned* __restrict__ Sb,
        const int2* __restrict__ sorted,
        const int* __restrict__ offs,
        const float* __restrict__ bias,
        float* __restrict__ out) {
    const int lane = threadIdx.x & 63;
    const int node = (blockIdx.x * 256 + threadIdx.x) >> 6;
    if (node >= N_NODES) return;

    const int half = lane >> 5;        // which record of the pair
    const int hl   = lane & 31;        // lane within half: feats 4hl..4hl+3

    const int beg = offs[node];
    const int end = (node == N_NODES - 1) ? N_EDGES : offs[node + 1];

    float a0 = 0.f, a1 = 0.f, a2 = 0.f, a3 = 0.f;

    for (int base = beg; base < end; base += 64) {
        const int m = min(64, end - base);
        int2 rec = make_int2(0, 0);
        if (base + lane < end) rec = sorted[base + lane];
        const int pairs = (m + 1) >> 1;

        int j = 0;
        for (; j + 4 <= pairs; j += 4) {
            int i0 = 2 * (j + 0) + half, i1 = 2 * (j + 1) + half;
            int i2 = 2 * (j + 2) + half, i3 = 2 * (j + 3) + half;
            int s0 = __shfl(rec.x, i0); int s1 = __shfl(rec.x, i1);
            int s2 = __shfl(rec.x, i2); int s3 = __shfl(rec.x, i3);
            float v0 = __int_as_float(__shfl(rec.y, i0));
            float v1 = __int_as_float(__shfl(rec.y, i1));
            float v2 = __int_as_float(__shfl(rec.y, i2));
            float v3 = __int_as_float(__shfl(rec.y, i3));
            uint2 p0 = ((const uint2*)(Sb + (size_t)s0 * 64))[hl];
            uint2 p1 = ((const uint2*)(Sb + (size_t)s1 * 64))[hl];
            uint2 p2 = ((const uint2*)(Sb + (size_t)s2 * 64))[hl];
            uint2 p3 = ((const uint2*)(Sb + (size_t)s3 * 64))[hl];
            a0 += v0 * __uint_as_float(p0.x << 16);
            a1 += v0 * __uint_as_float(p0.x & 0xFFFF0000u);
            a2 += v0 * __uint_as_float(p0.y << 16);
            a3 += v0 * __uint_as_float(p0.y & 0xFFFF0000u);
            a0 += v1 * __uint_as_float(p1.x << 16);
            a1 += v1 * __uint_as_float(p1.x & 0xFFFF0000u);
            a2 += v1 * __uint_as_float(p1.y << 16);
            a3 += v1 * __uint_as_float(p1.y & 0xFFFF0000u);
            a0 += v2 * __uint_as_float(p2.x << 16);
            a1 += v2 * __uint_as_float(p2.x & 0xFFFF0000u);
            a2 += v2 * __uint_as_float(p2.y << 16);
            a3 += v2 * __uint_as_float(p2.y & 0xFFFF0000u);
            a0 += v3 * __uint_as_float(p3.x << 16);
            a1 += v3 * __uint_as_float(p3.x & 0xFFFF0000u);
            a2 += v3 * __uint_as_float(p3.y << 16);
            a3 += v3 * __uint_as_float(p3.y & 0xFFFF0000u);
        }
        for (; j < pairs; ++j) {
            int i0 = 2 * j + half;
            int s0 = __shfl(rec.x, i0);
            float v0 = __int_as_float(__shfl(rec.y, i0));
            uint2 p0 = ((const uint2*)(Sb + (size_t)s0 * 64))[hl];
            a0 += v0 * __uint_as_float(p0.x << 16);
            a1 += v0 * __uint_as_float(p0.x & 0xFFFF0000u);
            a2 += v0 * __uint_as_float(p0.y << 16);
            a3 += v0 * __uint_as_float(p0.y & 0xFFFF0000u);
        }
    }

    // combine the two halves (feats 4hl..4hl+3 live in lanes hl and hl+32)
    a0 += __shfl(a0, lane ^ 32);
    a1 += __shfl(a1, lane ^ 32);
    a2 += __shfl(a2, lane ^ 32);
    a3 += __shfl(a3, lane ^ 32);

    if (half == 0) {
        float4 b4 = ((const float4*)bias)[hl];
        float4 r4 = make_float4(a0 + b4.x, a1 + b4.y, a2 + b4.z, a3 + b4.w);
        ((float4*)(out + (size_t)node * D))[hl] = r4;
    }
}

extern "C" void kernel_launch(void* const* d_in, const int* in_sizes, int n_in,
                              void* d_out, int out_size, void* d_ws, size_t ws_size,
                              hipStream_t stream) {
    const float* X    = (const float*)d_in[0];
    const int*   esrc = (const int*)  d_in[1];
    const int*   edst = (const int*)  d_in[2];
    const float* eval = (const float*)d_in[3];
    const float* W    = (const float*)d_in[4];
    const float* bias = (const float*)d_in[5];
    float* out = (float*)d_out;

    char* ws = (char*)d_ws;
    unsigned* SbU   = (unsigned*)(ws + OFF_SB);
    int2*     recs  = (int2*)    (ws + OFF_REC);
    int2*     srt2  = (int2*)    (ws + OFF_SORT2);
    int*      offs  = (int*)     (ws + OFF_OFFS);
    int*      ghist = (int*)     (ws + OFF_GHIST);
    int*      boffs = (int*)     (ws + OFF_BOFFS);
    int*      gcur  = (int*)     (ws + OFF_GCUR);

    // S = X @ W (bf16, MFMA)
    gemm_mfma<<<782, 256, 0, stream>>>(X, W, SbU);

    // Two-level counting sort of edges by dst (all scatters L2-resident)
    hipMemsetAsync(ghist, 0, K1C * 4, stream);
    hist_coarse<<<256, 256, 0, stream>>>(edst, ghist);
    scan_coarse<<<1, 256, 0, stream>>>(ghist, boffs, gcur);
    partition_edges<<<NCHUNK, 512, 0, stream>>>(esrc, edst, eval, gcur, recs);
    fine_sort<<<K1C, 256, 0, stream>>>(recs, boffs, offs, srt2);

    // Segmented reduce: out[n] = bias + sum val * S[src]
    reduce_segments<<<(N_NODES + 3) / 4, 256, 0, stream>>>(
        SbU, srt2, offs, bias, out);
}